// Round 1
// baseline (471.545 us; speedup 1.0000x reference)
//
#include <hip/hip_runtime.h>

// SpatialPool: fm [B=16, C=512, H=38, W=38] f32, replication pad 1,
// out[b, h*W+w, k*C+c] = fm[b, c, clamp(h+k/3-1), clamp(w+k%3-1)]
// Memory-bound transpose-gather: stage rows in LDS (w-contig reads),
// write c-contig coalesced stores.

#define BB 16
#define CC 512
#define HH 38
#define WW 38
#define HW (HH * WW)          // 1444
#define KK 9
#define CCH 128               // channel chunk per block
#define NCH (CC / CCH)        // 4
#define LSTRIDE 39            // LDS w-stride: 39 -> bank 7c%32, gcd(7,32)=1 conflict-free
#define NTHREADS 512

__global__ __launch_bounds__(NTHREADS) void spatial_pool_kernel(
    const float* __restrict__ fm, float* __restrict__ out)
{
    __shared__ float lds[3][CCH][LSTRIDE];   // 59,904 B -> 2 blocks/CU

    const int blk   = blockIdx.x;            // 0..2431
    const int chunk = blk & (NCH - 1);       // 0..3
    const int bh    = blk >> 2;              // 0..607
    const int h     = bh % HH;
    const int b     = bh / HH;
    const int c0    = chunk * CCH;

    // clamped source rows for di = 0,1,2
    const int r0 = (h - 1 < 0) ? 0 : h - 1;
    const int r1 = h;
    const int r2 = (h + 1 > HH - 1) ? HH - 1 : h + 1;

    // ---- stage: 3 rows x CCH channels x WW into LDS, coalesced along w ----
    const float* base = fm + ((size_t)b * CC + c0) * HW;
    const int NLOAD = 3 * CCH * WW;          // 14592
    for (int idx = threadIdx.x; idx < NLOAD; idx += NTHREADS) {
        int w  = idx % WW;
        int rc = idx / WW;                   // r*CCH + c
        int c  = rc & (CCH - 1);
        int r  = rc >> 7;
        int hr = (r == 0) ? r0 : ((r == 1) ? r1 : r2);
        lds[r][c][w] = base[c * HW + hr * WW + w];
    }
    __syncthreads();

    // ---- store: i -> (wk, c); per-wave uniform (w,k), consecutive c ----
    // out[((b*HW + h*WW + w)*KK + k)*CC + c0 + c] = lds[k/3][c][clamp(w+k%3-1)]
    float* outb = out + (((size_t)b * HW + (size_t)h * WW) * KK) * CC + c0;
    const int NST = WW * KK * CCH;           // 43776
    for (int i = threadIdx.x; i < NST; i += NTHREADS) {
        int c  = i & (CCH - 1);
        int wk = i >> 7;                     // w*KK + k, uniform per 64-lane wave
        int w  = wk / KK;
        int k  = wk - w * KK;
        int di = k / 3;
        int dj = k - di * 3;
        int wp = w + dj - 1;
        wp = (wp < 0) ? 0 : ((wp > WW - 1) ? WW - 1 : wp);
        outb[(size_t)wk * CC + c] = lds[di][c][wp];
    }
}

extern "C" void kernel_launch(void* const* d_in, const int* in_sizes, int n_in,
                              void* d_out, int out_size, void* d_ws, size_t ws_size,
                              hipStream_t stream) {
    const float* fm = (const float*)d_in[0];
    float* out = (float*)d_out;
    dim3 grid(BB * HH * NCH);                // 2432 blocks
    dim3 block(NTHREADS);
    spatial_pool_kernel<<<grid, block, 0, stream>>>(fm, out);
}

// Round 2
// 460.295 us; speedup vs baseline: 1.0244x; 1.0244x over previous
//
#include <hip/hip_runtime.h>

// SpatialPool: fm [B=16, C=512, H=38, W=38] f32, replication pad 1,
// out[b, (h*W+w)*9*C + k*C + c] = fm[b, c, clamp(h+k/3-1), clamp(w+k%3-1)]
//
// R1: scalar dword stores capped at ~3 TB/s (per-lane 4B stores + ~30 VALU
// per store). R2: w-major LDS [3][38][132] so the store side reads
// ds_read_b128 (c-contiguous) and writes global_store_dwordx4 (1 KB/wave).

#define BB 16
#define CC 512
#define HH 38
#define WW 38
#define HW (HH * WW)          // 1444
#define KK 9
#define CCH 128               // channel chunk per block
#define NCH (CC / CCH)        // 4
#define LC (CCH + 4)          // 132: rows 16B-aligned (132%4==0), bank step 4
#define NTHREADS 512

__global__ __launch_bounds__(NTHREADS) void spatial_pool_kernel(
    const float* __restrict__ fm, float* __restrict__ out)
{
    __shared__ float lds[3][WW][LC];         // 3*38*132*4 = 60,192 B -> 2 blocks/CU

    const int blk   = blockIdx.x;            // 0..2431
    const int chunk = blk & (NCH - 1);       // 0..3
    const int bh    = blk >> 2;              // 0..607
    const int h     = bh % HH;
    const int b     = bh / HH;
    const int c0    = chunk * CCH;

    // clamped source rows for di = 0,1,2
    const int r0 = (h - 1 < 0) ? 0 : h - 1;
    const int r1 = h;
    const int r2 = (h + 1 > HH - 1) ? HH - 1 : h + 1;

    // ---- stage: 3 rows x CCH channels x WW into LDS (transposed to w-major)
    // global float2 loads (rows are 8B-aligned: offsets all even), scalar LDS writes
    const float* base = fm + ((size_t)b * CC + c0) * HW;
    const int NL2 = 3 * CCH * (WW / 2);      // 7296 float2 loads
    for (int idx = threadIdx.x; idx < NL2; idx += NTHREADS) {
        int w2 = idx % (WW / 2);             // 0..18 (magic-div by 19)
        int rc = idx / (WW / 2);             // r*CCH + c
        int c  = rc & (CCH - 1);
        int r  = rc >> 7;
        int hr = (r == 0) ? r0 : ((r == 1) ? r1 : r2);
        const float2 v = *(const float2*)(base + c * HW + hr * WW + 2 * w2);
        lds[r][2 * w2 + 0][c] = v.x;
        lds[r][2 * w2 + 1][c] = v.y;
    }
    __syncthreads();

    // ---- store: float4 per lane; i -> (wk, c4); lanes 0..31 share wk ----
    // out float4 index: wk*(CC/4) + (c0/4) + c4
    float4* outb4 = (float4*)(out + (((size_t)b * HW + (size_t)h * WW) * KK) * CC + c0);
    const int NST4 = WW * KK * (CCH / 4);    // 38*9*32 = 10944
    for (int i = threadIdx.x; i < NST4; i += NTHREADS) {
        int c4 = i & 31;
        int wk = i >> 5;                     // w*KK + k, 0..341
        int w  = wk / KK;                    // magic-div
        int k  = wk - w * KK;
        int di = k / 3;
        int dj = k - di * 3;
        int wp = w + dj - 1;
        wp = (wp < 0) ? 0 : ((wp > WW - 1) ? WW - 1 : wp);
        const float4 v = *(const float4*)&lds[di][wp][c4 * 4];   // ds_read_b128
        outb4[(size_t)wk * (CC / 4) + c4] = v;                   // global_store_dwordx4
    }
}

extern "C" void kernel_launch(void* const* d_in, const int* in_sizes, int n_in,
                              void* d_out, int out_size, void* d_ws, size_t ws_size,
                              hipStream_t stream) {
    const float* fm = (const float*)d_in[0];
    float* out = (float*)d_out;
    dim3 grid(BB * HH * NCH);                // 2432 blocks
    dim3 block(NTHREADS);
    spatial_pool_kernel<<<grid, block, 0, stream>>>(fm, out);
}